// Round 1
// baseline (153.990 us; speedup 1.0000x reference)
//
#include <hip/hip_runtime.h>
#include <stdint.h>

namespace {

constexpr int T_TOTAL = 524288;
constexpr int KCOMP   = 64;
constexpr int CHUNK   = 128;   // timesteps per chain (one wave each); was 64.
                               // warm overhead drops 50% -> 25% of output steps
constexpr int WARM    = 32;    // 0.9^32*|v| ~ 5e-3, validated in prior session
constexpr int WAVES_PER_BLOCK = 4;
constexpr int BLOCK_T = CHUNK * WAVES_PER_BLOCK;   // 512 output steps per block
constexpr int NBLOCK  = T_TOTAL / BLOCK_T;         // 1024 blocks -> 4 blocks/CU
constexpr int LDS_ROWS = BLOCK_T + WARM;           // 544 rows x 16 B = 8.7 KB

typedef _Float16 half_t;

union H2 { uint32_t u; half_t h[2]; };

// pack two squared floats as f16 (RTN). f16: 11 mantissa bits vs bf16's 8;
// o^2 values are ~1e-4 scale, well inside f16 range (subnormal tail costs
// <1e-6 absolute in v -- negligible).
__device__ __forceinline__ uint32_t packh2(float x, float y) {
    H2 c; c.h[0] = (half_t)x; c.h[1] = (half_t)y; return c.u;
}

__global__ __launch_bounds__(256, 4) void garch_scan(
    const float4* __restrict__ rows,   // series (T, 8) fp32 = 2x float4 per row
    const float*  __restrict__ vars0,  // (64,)
    const float*  __restrict__ bias,   // (64,)
    const float*  __restrict__ Wx,     // (64, 8)
    const float*  __restrict__ Wh,     // (64,)
    float*        __restrict__ out)    // (T, 64) fp32
{
    // one uint4 per timestep row: 8 x f16(o^2). Same 16B/step LDS cost as the
    // bf16 version, but consumed via v_fma_mix_f32 (no unpack VALU ops) and
    // ~8x less quantization error.
    __shared__ uint4 sq[LDS_ROWS];

    const int tid  = threadIdx.x;
    const int lane = tid & 63;
    const int wave = tid >> 6;
    const int blk  = blockIdx.x;
    const int blk_t0 = blk * BLOCK_T;

    // ---- cooperative stage: bulk coalesced load, square+pack once ----
    // LDS row L holds o^2 for global t = blk_t0 - WARM + L.
    const long t_base = (long)blk_t0 - WARM;
    for (int idx = tid; idx < LDS_ROWS; idx += 256) {
        long t = t_base + idx;
        if (t < 0) t = 0;              // blk 0 pre-region (never read by chunk 0)
        float4 ra = rows[2 * t + 0];
        float4 rb = rows[2 * t + 1];
        uint4 p;
        p.x = packh2(ra.x * ra.x, ra.y * ra.y);
        p.y = packh2(ra.z * ra.z, ra.w * ra.w);
        p.z = packh2(rb.x * rb.x, rb.y * rb.y);
        p.w = packh2(rb.z * rb.z, rb.w * rb.w);
        sq[idx] = p;
    }

    // per-lane constants (one mixture component k per lane)
    const int k = lane;
    const float w0 = Wx[k*8+0], w1 = Wx[k*8+1], w2 = Wx[k*8+2], w3 = Wx[k*8+3];
    const float w4 = Wx[k*8+4], w5 = Wx[k*8+5], w6 = Wx[k*8+6], w7 = Wx[k*8+7];
    const float a  = Wh[k];
    // all terms nonnegative -> relu no-op; folding +1e-6 pre-relu is exact
    const float be = bias[k] + 1e-6f;

    __syncthreads();

    const int chunk = blk * WAVES_PER_BLOCK + wave;
    float v;
    if (chunk == 0) {
        v = vars0[k];                  // exact start, no warm-up
    } else {
        v = 0.0f;                      // contraction warm-up from LDS
        const int lw = wave * CHUNK;   // local row of (t0 - WARM)
        #pragma unroll 8
        for (int i = 0; i < WARM; ++i) {
            uint4 u = sq[lw + i];      // broadcast: all lanes same addr
            H2 c0, c1, c2, c3;
            c0.u = u.x; c1.u = u.y; c2.u = u.z; c3.u = u.w;
            float d = be;
            // fma(fpext(f16), f32, f32) -> v_fma_mix_f32: 1 VALU op per term
            d = fmaf(w0, (float)c0.h[0], d); d = fmaf(w1, (float)c0.h[1], d);
            d = fmaf(w2, (float)c1.h[0], d); d = fmaf(w3, (float)c1.h[1], d);
            d = fmaf(w4, (float)c2.h[0], d); d = fmaf(w5, (float)c2.h[1], d);
            d = fmaf(w6, (float)c3.h[0], d); d = fmaf(w7, (float)c3.h[1], d);
            v = fmaxf(fmaf(a, v, d), 0.0f);
        }
    }

    // ---- main chunk: 1x ds_read_b128/step + fire-and-forget nt stores ----
    const int t0 = chunk * CHUNK;
    const int lm = wave * CHUNK + WARM;       // local row of t0
    float* op = out + (size_t)t0 * KCOMP + k; // 64 lanes -> 256B contiguous/step
    #pragma unroll 8
    for (int i = 0; i < CHUNK; ++i) {
        uint4 u = sq[lm + i];
        H2 c0, c1, c2, c3;
        c0.u = u.x; c1.u = u.y; c2.u = u.z; c3.u = u.w;
        float d = be;
        d = fmaf(w0, (float)c0.h[0], d); d = fmaf(w1, (float)c0.h[1], d);
        d = fmaf(w2, (float)c1.h[0], d); d = fmaf(w3, (float)c1.h[1], d);
        d = fmaf(w4, (float)c2.h[0], d); d = fmaf(w5, (float)c2.h[1], d);
        d = fmaf(w6, (float)c3.h[0], d); d = fmaf(w7, (float)c3.h[1], d);
        v = fmaxf(fmaf(a, v, d), 0.0f);
        // output is write-once, never re-read by us: keep it out of L2
        __builtin_nontemporal_store(v, op + (size_t)i * KCOMP);
    }
}

} // namespace

extern "C" void kernel_launch(void* const* d_in, const int* in_sizes, int n_in,
                              void* d_out, int out_size, void* d_ws, size_t ws_size,
                              hipStream_t stream) {
    const float4* series = (const float4*)d_in[0];
    const float*  vars0  = (const float*)d_in[1];
    const float*  bias   = (const float*)d_in[2];
    const float*  Wx     = (const float*)d_in[3];
    const float*  Wh     = (const float*)d_in[4];
    float*        out    = (float*)d_out;
    garch_scan<<<NBLOCK, 256, 0, stream>>>(series, vars0, bias, Wx, Wh, out);
}